// Round 17
// baseline (507.922 us; speedup 1.0000x reference)
//
#include <hip/hip_runtime.h>
#include <math.h>

#define Bb 2
#define Tt 4096
#define Cc 768
#define Hh 12
#define Dd 64

typedef __attribute__((ext_vector_type(8))) short short8;
typedef __attribute__((ext_vector_type(4))) float f32x4;
typedef __attribute__((ext_vector_type(4))) unsigned short u16x4;

static __device__ __forceinline__ unsigned short f2bf(float f) {
    unsigned u = __float_as_uint(f);
    u += 0x7FFF + ((u >> 16) & 1);          // round-to-nearest-even
    return (unsigned short)(u >> 16);
}

static __device__ __forceinline__ float ex2(float x) {
    return __builtin_amdgcn_exp2f(x);
}

static __device__ __forceinline__ void gload16(const void* g, void* l) {
    __builtin_amdgcn_global_load_lds(
        (const __attribute__((address_space(1))) unsigned*)g,
        (__attribute__((address_space(3))) unsigned*)l, 16, 0, 0);
}

// ---------------------------------------------------------------------------
// fp32 -> bf16 elementwise convert (8 elems/thread)
// ---------------------------------------------------------------------------
__global__ __launch_bounds__(256)
void cvt_bf16(const float* __restrict__ in, unsigned short* __restrict__ out, int n8) {
    int i = blockIdx.x * 256 + threadIdx.x;
    if (i >= n8) return;
    float4 a = *(const float4*)(in + (size_t)i * 8);
    float4 b = *(const float4*)(in + (size_t)i * 8 + 4);
    union { short8 v; unsigned short u[8]; } p;
    p.u[0] = f2bf(a.x); p.u[1] = f2bf(a.y); p.u[2] = f2bf(a.z); p.u[3] = f2bf(a.w);
    p.u[4] = f2bf(b.x); p.u[5] = f2bf(b.y); p.u[6] = f2bf(b.z); p.u[7] = f2bf(b.w);
    *(short8*)(out + (size_t)i * 8) = p.v;
}

// ---------------------------------------------------------------------------
// W[K][N] fp32 -> Wt[N][K] bf16 (64x64 LDS tile transpose)
// ---------------------------------------------------------------------------
__global__ __launch_bounds__(256)
void transpose_w(const float* __restrict__ W, unsigned short* __restrict__ Wt,
                 int K, int N) {
    __shared__ __align__(16) unsigned short Tl[64][72];
    int n0 = blockIdx.x * 64, k0 = blockIdx.y * 64;
    int t = threadIdx.x;
    int r = t >> 2, c = (t & 3) * 16;
    const float* wp = W + (size_t)(k0 + r) * N + n0 + c;
    #pragma unroll
    for (int j = 0; j < 16; j += 4) {
        float4 v = *(const float4*)(wp + j);
        Tl[c + j + 0][r] = f2bf(v.x);
        Tl[c + j + 1][r] = f2bf(v.y);
        Tl[c + j + 2][r] = f2bf(v.z);
        Tl[c + j + 3][r] = f2bf(v.w);
    }
    __syncthreads();
    unsigned short* op = Wt + (size_t)(n0 + r) * K + k0 + c;
    *(short8*)op       = *(const short8*)&Tl[r][c];
    *(short8*)(op + 8) = *(const short8*)&Tl[r][c + 8];
}

// ---------------------------------------------------------------------------
// bf16 MFMA GEMM, 128x128 tile, BK=64, 256 threads, global_load_lds staging.
// gemm1 (BF16OUT=true, kpk/vpk set):
//   n0 <  768  : Q columns -> qb [token][768] bf16, scaled 0.125*log2e
//   768..1535  : K columns -> kpk fragment-packed (transpose via LDS)
//   n0 >= 1536 : V columns -> vpk fragment-packed (transpose via LDS)
// gemm2 (BF16OUT=false): fp32 out, stride N.
// Pack layout (ushorts): [(b*Hh+h)*64 + tile][frag 0..7][lane 0..63][8]
//   K frag f=kh*4+kt*2+ks, lane(lr,g): K[tile*64+kh*32+kt*16+lr][ks*32+g*8+j]
//   V frag f=dt*2+kh,      lane(lr,g): V^T[dt*16+lr][tile*64+kh*32+g*8+j]
// ---------------------------------------------------------------------------
template<bool BF16OUT>
__global__ __launch_bounds__(256)
void gemm_mfma(const unsigned short* __restrict__ A, const unsigned short* __restrict__ Bt,
               const float* __restrict__ bias, void* __restrict__ Cout,
               int M, int N, int K,
               unsigned short* __restrict__ kpk, unsigned short* __restrict__ vpk) {
    union SmemU {
        unsigned short ab[2][128][64];   // staging: [0]=A tile, [1]=B tile
        unsigned short tv[128][136];     // transpose epilogue buffer
    };
    __shared__ __align__(16) SmemU sh;
    const int tid = threadIdx.x;
    const int wid = tid >> 6, lane = tid & 63;
    const int lr = lane & 15, g = lane >> 4;
    const int wr = wid >> 1, wc = wid & 1;
    const int m0 = blockIdx.y * 128, n0 = blockIdx.x * 128;
    const int srow = lane >> 3;
    const int scol = (lane & 7) * 8;

    f32x4 acc[4][4] = {};

    for (int k0 = 0; k0 < K; k0 += 64) {
        #pragma unroll
        for (int j = 0; j < 4; ++j) {
            int ci = wid * 4 + j;
            int row = ci * 8 + srow;
            gload16(A  + (size_t)(m0 + row) * K + k0 + scol, &sh.ab[0][ci * 8][0]);
            gload16(Bt + (size_t)(n0 + row) * K + k0 + scol, &sh.ab[1][ci * 8][0]);
        }
        __syncthreads();
        #pragma unroll
        for (int ks = 0; ks < 2; ++ks) {
            short8 af[4], bfr[4];
            #pragma unroll
            for (int m = 0; m < 4; ++m)
                af[m] = *(const short8*)&sh.ab[0][wr * 64 + m * 16 + lr][ks * 32 + g * 8];
            #pragma unroll
            for (int n = 0; n < 4; ++n)
                bfr[n] = *(const short8*)&sh.ab[1][wc * 64 + n * 16 + lr][ks * 32 + g * 8];
            #pragma unroll
            for (int m = 0; m < 4; ++m)
                #pragma unroll
                for (int n = 0; n < 4; ++n)
                    acc[m][n] = __builtin_amdgcn_mfma_f32_16x16x32_bf16(
                        af[m], bfr[n], acc[m][n], 0, 0, 0);
        }
        __syncthreads();
    }

    if (BF16OUT && vpk != nullptr && n0 >= 2 * Cc) {
        // ---- V pack epilogue: acc -> LDS transposed [dcol][token] -> vpk ----
        #pragma unroll
        for (int n = 0; n < 4; ++n) {
            int tcol = wc * 64 + n * 16 + lr;
            float bv = bias[n0 + tcol];
            #pragma unroll
            for (int m = 0; m < 4; ++m) {
                int trow = wr * 64 + m * 16 + g * 4;
                #pragma unroll
                for (int r = 0; r < 4; ++r)
                    sh.tv[tcol][trow + r] = f2bf(acc[m][n][r] + bv);
            }
        }
        __syncthreads();
        const int dlocal = tid >> 1;            // 0..127 (d column of tile)
        const int th     = (tid & 1) * 64;      // token half
        const int hd     = ((n0 - 2 * Cc) >> 6) + (dlocal >> 6);
        const int dl     = dlocal & 63;
        const int dt     = dl >> 4, lrv = dl & 15;
        const int token  = m0 + th;
        const int bq     = token >> 12;
        const int tile   = (token & (Tt - 1)) >> 6;
        unsigned short* tb = vpk + (size_t)((bq * Hh + hd) * 64 + tile) * 4096;
        #pragma unroll
        for (int cj = 0; cj < 8; ++cj) {
            int khv = cj >> 2, gv = cj & 3;
            unsigned short* dst = tb + (dt * 2 + khv) * 512 + (gv * 16 + lrv) * 8;
            *(short8*)dst = *(const short8*)&sh.tv[dlocal][th + cj * 8];
        }
        return;
    }

    if (BF16OUT && kpk != nullptr && n0 >= Cc) {
        // ---- K pack epilogue: acc -> LDS transposed [token][dcol] -> kpk ----
        #pragma unroll
        for (int n = 0; n < 4; ++n) {
            int tcol = wc * 64 + n * 16 + lr;
            float bv = bias[n0 + tcol];
            #pragma unroll
            for (int m = 0; m < 4; ++m) {
                int trow = wr * 64 + m * 16 + g * 4;
                #pragma unroll
                for (int r = 0; r < 4; ++r)
                    sh.tv[trow + r][tcol] = f2bf(acc[m][n][r] + bv);
            }
        }
        __syncthreads();
        #pragma unroll
        for (int c = 0; c < 8; ++c) {
            int s = tid + 256 * c;              // 0..2047
            int ln = s & 63;
            int f  = (s >> 6) & 7;
            int hh = (s >> 9) & 1;
            int sub = s >> 10;
            int khk = f >> 2, ktk = (f >> 1) & 1, ksk = f & 1;
            int gk = ln >> 4, lrk = ln & 15;
            int tokl = sub * 64 + khk * 32 + ktk * 16 + lrk;
            int dl   = hh * 64 + ksk * 32 + gk * 8;
            int token = m0 + sub * 64;
            int bq    = token >> 12;
            int tile  = (token & (Tt - 1)) >> 6;
            int hd    = ((n0 - Cc) >> 6) + hh;
            unsigned short* dst = kpk + (size_t)((bq * Hh + hd) * 64 + tile) * 4096
                                  + f * 512 + ln * 8;
            *(short8*)dst = *(const short8*)&sh.tv[tokl][dl];
        }
        return;
    }

    // ---- normal epilogue: Q columns (bf16, scaled) or fp32 out ----
    const float qscale = 0.125f * 1.44269504088896340736f;
    #pragma unroll
    for (int n = 0; n < 4; ++n) {
        int coln = n0 + wc * 64 + n * 16 + lr;
        float bv = bias[coln];
        #pragma unroll
        for (int m = 0; m < 4; ++m) {
            int rowb = m0 + wr * 64 + m * 16 + g * 4;
            #pragma unroll
            for (int r = 0; r < 4; ++r) {
                float v = acc[m][n][r] + bv;
                if (BF16OUT)
                    ((unsigned short*)Cout)[(size_t)(rowb + r) * Cc + coln] =
                        f2bf(v * qscale);
                else
                    ((float*)Cout)[(size_t)(rowb + r) * N + coln] = v;
            }
        }
    }
}

// ---------------------------------------------------------------------------
// Flash attention, 16x16x32 MFMA, swapped QK^T, fixed-shift softmax,
// zero-LDS K/V (L2-resident fragment-packed buffers), barrier-free K-loop.
// SOFTWARE PIPELINE (depth 1, enabled by the barrier-free loop):
//   prologue: load K(0), compute QK(0)
//   iter ts : consume pre-computed scores st; issue V(ts) + K(ts+1) loads;
//             softmax + cvt + shfl issue; QK(ts+1) MFMAs fill the bpermute
//             latency; then PV(ts).
// 512 threads = 8 waves = 4 q-strips(16q) x 2 key-halves(32k); split-K
// partials combine by plain addition (fixed-shift) through LDS per pass.
// Causal PAIR scheduling (65-tile stream), XCD-colocated grid.
// ---------------------------------------------------------------------------
__global__ __launch_bounds__(512, 6)
void attn_mfma(const unsigned short* __restrict__ qb,
               const unsigned short* __restrict__ kpk,
               const unsigned short* __restrict__ vpk,
               unsigned short* __restrict__ outb) {
    // decode: id = xcd + 8*(P + 32*j), H2 = xcd + 8*j  (bijective, 768 blocks)
    const int nid  = blockIdx.x;
    const int xcd  = nid & 7;
    const int rest = nid >> 3;
    const int P    = rest & 31;                // pair: high 63-P, low P
    const int H2   = xcd + 8 * (rest >> 5);
    const int hd   = H2 % Hh;
    const int b    = H2 / Hh;
    const int tid = threadIdx.x;
    const int wid = tid >> 6, lane = tid & 63;
    const int strip = wid & 3, kh = wid >> 2;  // q-strip (16q), key-half (32k)
    const int lr = lane & 15, g = lane >> 4;

    __shared__ __align__(16) float combO[4][64][16];
    __shared__ float combL[4][64];

    const unsigned short* qbase = qb + (size_t)b * Tt * Cc;
    const unsigned short* kbase = kpk + (size_t)((b * Hh + hd) * 64) * 4096;
    const unsigned short* vbase = vpk + (size_t)((b * Hh + hd) * 64) * 4096;

    const int ntA = 64 - P;
    const int qA  = (63 - P) * 64 + strip * 16 + lr;
    const int qB  = P * 64 + strip * 16 + lr;

    // fragment offsets within a tile (ushorts)
    const int kfo = kh * 2048 + lane * 8;
    const int vfo = kh * 512 + lane * 8;

    short8 qf0, qf1;
    {
        const unsigned short* qp = qbase + (size_t)qA * Cc + hd * Dd;
        qf0 = *(const short8*)(qp + g * 8);
        qf1 = *(const short8*)(qp + 32 + g * 8);
    }

    const int laneA = lr + ((g & 1) << 5);     // src lane for P-relayout
    const int laneB = laneA + 16;
    const int asel  = g >> 1;

    f32x4 o[4];
    #pragma unroll
    for (int dt = 0; dt < 4; ++dt) o[dt] = (f32x4){0.f, 0.f, 0.f, 0.f};
    float lpart = 0.f;
    int myq = qA;

    auto combine_epilogue = [&]() {
        if (kh) {
            #pragma unroll
            for (int dt = 0; dt < 4; ++dt)
                *(f32x4*)&combO[strip][lane][dt * 4] = o[dt];
            combL[strip][lane] = lpart;
        }
        __syncthreads();
        if (!kh) {
            float l_r = lpart + combL[strip][lane];
            l_r += __shfl_xor(l_r, 16);
            l_r += __shfl_xor(l_r, 32);
            float inv = 1.f / fmaxf(l_r, 1e-37f);
            unsigned short* op = outb + ((size_t)b * Tt + myq) * Cc + hd * Dd + g * 4;
            #pragma unroll
            for (int dt = 0; dt < 4; ++dt) {
                f32x4 t2 = *(const f32x4*)&combO[strip][lane][dt * 4];
                u16x4 w;
                #pragma unroll
                for (int r = 0; r < 4; ++r) w[r] = f2bf((o[dt][r] + t2[r]) * inv);
                *(u16x4*)(op + dt * 16) = w;
            }
        }
        __syncthreads();
    };

    // ---- pipeline prologue: K frags + QK for tile stream index 0 ----
    f32x4 stn0, stn1;
    {
        short8 k0 = *(const short8*)(kbase + kfo);
        short8 k1 = *(const short8*)(kbase + kfo + 512);
        short8 k2 = *(const short8*)(kbase + kfo + 1024);
        short8 k3 = *(const short8*)(kbase + kfo + 1536);
        f32x4 a = (f32x4){0.f, 0.f, 0.f, 0.f};
        a = __builtin_amdgcn_mfma_f32_16x16x32_bf16(k0, qf0, a, 0, 0, 0);
        a = __builtin_amdgcn_mfma_f32_16x16x32_bf16(k1, qf1, a, 0, 0, 0);
        stn0 = a;
        a = (f32x4){0.f, 0.f, 0.f, 0.f};
        a = __builtin_amdgcn_mfma_f32_16x16x32_bf16(k2, qf0, a, 0, 0, 0);
        a = __builtin_amdgcn_mfma_f32_16x16x32_bf16(k3, qf1, a, 0, 0, 0);
        stn1 = a;
    }

    #pragma unroll 1
    for (int ts = 0; ts < 65; ++ts) {
        const int inA = (ts < ntA) ? 1 : 0;
        const int kbt = inA ? ts : ts - ntA;
        const int nt  = inA ? ntA : (65 - ntA);

        // current tile scores (pre-computed)
        f32x4 st[2];
        st[0] = stn0; st[1] = stn1;

        // ---- V frags for current tile (needed at PV; latency under softmax)
        const unsigned short* vt_ = vbase + (size_t)kbt * 4096;
        short8 vf0 = *(const short8*)(vt_ + vfo);
        short8 vf1 = *(const short8*)(vt_ + vfo + 1024);
        short8 vf2 = *(const short8*)(vt_ + vfo + 2048);
        short8 vf3 = *(const short8*)(vt_ + vfo + 3072);

        // ---- K frags for NEXT tile (consumed by QK below; L2 latency
        //      covered by softmax+relayout) ----
        short8 kn0, kn1, kn2, kn3;
        const int have_next = (ts + 1 < 65);
        if (have_next) {
            int tn = (ts + 1 < ntA) ? ts + 1 : ts + 1 - ntA;
            const unsigned short* kt_ = kbase + (size_t)tn * 4096;
            kn0 = *(const short8*)(kt_ + kfo);
            kn1 = *(const short8*)(kt_ + kfo + 512);
            kn2 = *(const short8*)(kt_ + kfo + 1024);
            kn3 = *(const short8*)(kt_ + kfo + 1536);
        }

        // ---- causal mask (diagonal tile of the current pass only) ----
        if (kbt == nt - 1) {
            #pragma unroll
            for (int kt = 0; kt < 2; ++kt)
                #pragma unroll
                for (int r = 0; r < 4; ++r)
                    if (kbt * 64 + kh * 32 + kt * 16 + g * 4 + r > myq)
                        st[kt][r] = -1e30f;
        }

        // ---- fixed-shift softmax ----
        float psum = 0.f;
        #pragma unroll
        for (int kt = 0; kt < 2; ++kt)
            #pragma unroll
            for (int r = 0; r < 4; ++r) {
                float p = ex2(st[kt][r]);
                st[kt][r] = p;
                psum += p;
            }
        lpart += psum;

        // ---- cvt + shfl issue (results needed after next-tile QK) ----
        unsigned up[2][2];
        #pragma unroll
        for (int kt = 0; kt < 2; ++kt) {
            asm("v_cvt_pk_bf16_f32 %0, %1, %2"
                : "=v"(up[kt][0]) : "v"(st[kt][0]), "v"(st[kt][1]));
            asm("v_cvt_pk_bf16_f32 %0, %1, %2"
                : "=v"(up[kt][1]) : "v"(st[kt][2]), "v"(st[kt][3]));
        }
        unsigned wa0 = __shfl(up[0][0], laneA);
        unsigned wb0 = __shfl(up[1][0], laneA);
        unsigned wa1 = __shfl(up[0][1], laneA);
        unsigned wb1 = __shfl(up[1][1], laneA);
        unsigned wa2 = __shfl(up[0][0], laneB);
        unsigned wb2 = __shfl(up[1][0], laneB);
        unsigned wa3 = __shfl(up[0][1], laneB);
        unsigned wb3 = __shfl(up[1][1], laneB);

        // ---- next-tile QK (independent MFMA work filling bpermute latency)
        if (have_next) {
            if (ts + 1 == ntA) {   // crossing into pass B: switch Q frags
                const unsigned short* qp = qbase + (size_t)qB * Cc + hd * Dd;
                qf0 = *(const short8*)(qp + g * 8);
                qf1 = *(const short8*)(qp + 32 + g * 8);
            }
            f32x4 a = (f32x4){0.f, 0.f, 0.f, 0.f};
            a = __builtin_amdgcn_mfma_f32_16x16x32_bf16(kn0, qf0, a, 0, 0, 0);
            a = __builtin_amdgcn_mfma_f32_16x16x32_bf16(kn1, qf1, a, 0, 0, 0);
            stn0 = a;
            a = (f32x4){0.f, 0.f, 0.f, 0.f};
            a = __builtin_amdgcn_mfma_f32_16x16x32_bf16(kn2, qf0, a, 0, 0, 0);
            a = __builtin_amdgcn_mfma_f32_16x16x32_bf16(kn3, qf1, a, 0, 0, 0);
            stn1 = a;
        }

        // ---- PV for current tile ----
        union { unsigned w[4]; short8 v; } pb;
        pb.w[0] = asel ? wb0 : wa0;
        pb.w[1] = asel ? wb1 : wa1;
        pb.w[2] = asel ? wb2 : wa2;
        pb.w[3] = asel ? wb3 : wa3;
        o[0] = __builtin_amdgcn_mfma_f32_16x16x32_bf16(vf0, pb.v, o[0], 0, 0, 0);
        o[1] = __builtin_amdgcn_mfma_f32_16x16x32_bf16(vf1, pb.v, o[1], 0, 0, 0);
        o[2] = __builtin_amdgcn_mfma_f32_16x16x32_bf16(vf2, pb.v, o[2], 0, 0, 0);
        o[3] = __builtin_amdgcn_mfma_f32_16x16x32_bf16(vf3, pb.v, o[3], 0, 0, 0);

        // ---- pass-A finish: combine key-halves, write out, reset for B ----
        if (ts == ntA - 1) {
            combine_epilogue();
            #pragma unroll
            for (int dt = 0; dt < 4; ++dt) o[dt] = (f32x4){0.f, 0.f, 0.f, 0.f};
            lpart = 0.f;
            myq = qB;
        }
    }

    combine_epilogue();
}

// ---------------------------------------------------------------------------
extern "C" void kernel_launch(void* const* d_in, const int* in_sizes, int n_in,
                              void* d_out, int out_size, void* d_ws, size_t ws_size,
                              hipStream_t stream) {
    const float* x    = (const float*)d_in[0];
    const float* Wqkv = (const float*)d_in[1];
    const float* bqkv = (const float*)d_in[2];
    const float* Wout = (const float*)d_in[3];
    const float* bout = (const float*)d_in[4];
    float* out = (float*)d_out;

    const int M = Bb * Tt;          // 8192
    const int N1 = 3 * Cc;          // 2304

    char* p = (char*)d_ws;
    unsigned short* qbuf  = (unsigned short*)p; p += (size_t)M * Cc * 2;        // Q rows
    unsigned short* xb    = (unsigned short*)p; p += (size_t)M * Cc * 2;
    unsigned short* wqkvt = (unsigned short*)p; p += (size_t)N1 * Cc * 2;
    unsigned short* woutt = (unsigned short*)p; p += (size_t)Cc * Cc * 2;
    unsigned short* kpk   = (unsigned short*)p; p += (size_t)Bb * Hh * 64 * 4096 * 2;
    unsigned short* vpk   = (unsigned short*)p; p += (size_t)Bb * Hh * 64 * 4096 * 2;
    unsigned short* attb  = (unsigned short*)p; p += (size_t)M * Cc * 2;

    cvt_bf16<<<dim3((M * Cc / 8 + 255) / 256), dim3(256), 0, stream>>>(x, xb, M * Cc / 8);
    transpose_w<<<dim3(N1 / 64, Cc / 64), dim3(256), 0, stream>>>(Wqkv, wqkvt, Cc, N1);
    transpose_w<<<dim3(Cc / 64, Cc / 64), dim3(256), 0, stream>>>(Wout, woutt, Cc, Cc);

    // qkv GEMM: Q -> qbuf rows (scaled), K -> kpk frags, V -> vpk frags
    gemm_mfma<true><<<dim3(N1 / 128, M / 128), dim3(256), 0, stream>>>(
        xb, wqkvt, bqkv, qbuf, M, N1, Cc, kpk, vpk);

    // 32 causal pairs of 64-q blocks per (b,h); XCD-colocated; zero-LDS KV;
    // software-pipelined tile stream.
    attn_mfma<<<dim3(32 * Hh * Bb), dim3(512), 0, stream>>>(qbuf, kpk, vpk, attb);

    gemm_mfma<false><<<dim3(Cc / 128, M / 128), dim3(256), 0, stream>>>(
        attb, woutt, bout, out, M, Cc, Cc, nullptr, nullptr);
}

// Round 18
// 198.232 us; speedup vs baseline: 2.5623x; 2.5623x over previous
//
#include <hip/hip_runtime.h>
#include <math.h>

#define Bb 2
#define Tt 4096
#define Cc 768
#define Hh 12
#define Dd 64

typedef __attribute__((ext_vector_type(8))) short short8;
typedef __attribute__((ext_vector_type(4))) float f32x4;
typedef __attribute__((ext_vector_type(4))) unsigned short u16x4;

static __device__ __forceinline__ unsigned short f2bf(float f) {
    unsigned u = __float_as_uint(f);
    u += 0x7FFF + ((u >> 16) & 1);          // round-to-nearest-even
    return (unsigned short)(u >> 16);
}

static __device__ __forceinline__ float ex2(float x) {
    return __builtin_amdgcn_exp2f(x);
}

static __device__ __forceinline__ void gload16(const void* g, void* l) {
    __builtin_amdgcn_global_load_lds(
        (const __attribute__((address_space(1))) unsigned*)g,
        (__attribute__((address_space(3))) unsigned*)l, 16, 0, 0);
}

// ---------------------------------------------------------------------------
// fp32 -> bf16 elementwise convert (8 elems/thread)
// ---------------------------------------------------------------------------
__global__ __launch_bounds__(256)
void cvt_bf16(const float* __restrict__ in, unsigned short* __restrict__ out, int n8) {
    int i = blockIdx.x * 256 + threadIdx.x;
    if (i >= n8) return;
    float4 a = *(const float4*)(in + (size_t)i * 8);
    float4 b = *(const float4*)(in + (size_t)i * 8 + 4);
    union { short8 v; unsigned short u[8]; } p;
    p.u[0] = f2bf(a.x); p.u[1] = f2bf(a.y); p.u[2] = f2bf(a.z); p.u[3] = f2bf(a.w);
    p.u[4] = f2bf(b.x); p.u[5] = f2bf(b.y); p.u[6] = f2bf(b.z); p.u[7] = f2bf(b.w);
    *(short8*)(out + (size_t)i * 8) = p.v;
}

// ---------------------------------------------------------------------------
// W[K][N] fp32 -> Wt[N][K] bf16 (64x64 LDS tile transpose)
// ---------------------------------------------------------------------------
__global__ __launch_bounds__(256)
void transpose_w(const float* __restrict__ W, unsigned short* __restrict__ Wt,
                 int K, int N) {
    __shared__ __align__(16) unsigned short Tl[64][72];
    int n0 = blockIdx.x * 64, k0 = blockIdx.y * 64;
    int t = threadIdx.x;
    int r = t >> 2, c = (t & 3) * 16;
    const float* wp = W + (size_t)(k0 + r) * N + n0 + c;
    #pragma unroll
    for (int j = 0; j < 16; j += 4) {
        float4 v = *(const float4*)(wp + j);
        Tl[c + j + 0][r] = f2bf(v.x);
        Tl[c + j + 1][r] = f2bf(v.y);
        Tl[c + j + 2][r] = f2bf(v.z);
        Tl[c + j + 3][r] = f2bf(v.w);
    }
    __syncthreads();
    unsigned short* op = Wt + (size_t)(n0 + r) * K + k0 + c;
    *(short8*)op       = *(const short8*)&Tl[r][c];
    *(short8*)(op + 8) = *(const short8*)&Tl[r][c + 8];
}

// ---------------------------------------------------------------------------
// bf16 MFMA GEMM, 128x128 tile, BK=64, 256 threads, global_load_lds staging.
// gemm1 (BF16OUT=true, kpk/vpk set):
//   n0 <  768  : Q columns -> qb [token][768] bf16, scaled 0.125*log2e
//   768..1535  : K columns -> kpk fragment-packed (transpose via LDS)
//   n0 >= 1536 : V columns -> vpk fragment-packed (transpose via LDS)
// gemm2 (BF16OUT=false): fp32 out, stride N.
// Pack layout (ushorts): [(b*Hh+h)*64 + tile][frag 0..7][lane 0..63][8]
//   K frag f=kh*4+kt*2+ks, lane(lr,g): K[tile*64+kh*32+kt*16+lr][ks*32+g*8+j]
//   V frag f=dt*2+kh,      lane(lr,g): V^T[dt*16+lr][tile*64+kh*32+g*8+j]
// ---------------------------------------------------------------------------
template<bool BF16OUT>
__global__ __launch_bounds__(256)
void gemm_mfma(const unsigned short* __restrict__ A, const unsigned short* __restrict__ Bt,
               const float* __restrict__ bias, void* __restrict__ Cout,
               int M, int N, int K,
               unsigned short* __restrict__ kpk, unsigned short* __restrict__ vpk) {
    union SmemU {
        unsigned short ab[2][128][64];   // staging: [0]=A tile, [1]=B tile
        unsigned short tv[128][136];     // transpose epilogue buffer
    };
    __shared__ __align__(16) SmemU sh;
    const int tid = threadIdx.x;
    const int wid = tid >> 6, lane = tid & 63;
    const int lr = lane & 15, g = lane >> 4;
    const int wr = wid >> 1, wc = wid & 1;
    const int m0 = blockIdx.y * 128, n0 = blockIdx.x * 128;
    const int srow = lane >> 3;
    const int scol = (lane & 7) * 8;

    f32x4 acc[4][4] = {};

    for (int k0 = 0; k0 < K; k0 += 64) {
        #pragma unroll
        for (int j = 0; j < 4; ++j) {
            int ci = wid * 4 + j;
            int row = ci * 8 + srow;
            gload16(A  + (size_t)(m0 + row) * K + k0 + scol, &sh.ab[0][ci * 8][0]);
            gload16(Bt + (size_t)(n0 + row) * K + k0 + scol, &sh.ab[1][ci * 8][0]);
        }
        __syncthreads();
        #pragma unroll
        for (int ks = 0; ks < 2; ++ks) {
            short8 af[4], bfr[4];
            #pragma unroll
            for (int m = 0; m < 4; ++m)
                af[m] = *(const short8*)&sh.ab[0][wr * 64 + m * 16 + lr][ks * 32 + g * 8];
            #pragma unroll
            for (int n = 0; n < 4; ++n)
                bfr[n] = *(const short8*)&sh.ab[1][wc * 64 + n * 16 + lr][ks * 32 + g * 8];
            #pragma unroll
            for (int m = 0; m < 4; ++m)
                #pragma unroll
                for (int n = 0; n < 4; ++n)
                    acc[m][n] = __builtin_amdgcn_mfma_f32_16x16x32_bf16(
                        af[m], bfr[n], acc[m][n], 0, 0, 0);
        }
        __syncthreads();
    }

    if (BF16OUT && vpk != nullptr && n0 >= 2 * Cc) {
        // ---- V pack epilogue: acc -> LDS transposed [dcol][token] -> vpk ----
        #pragma unroll
        for (int n = 0; n < 4; ++n) {
            int tcol = wc * 64 + n * 16 + lr;
            float bv = bias[n0 + tcol];
            #pragma unroll
            for (int m = 0; m < 4; ++m) {
                int trow = wr * 64 + m * 16 + g * 4;
                #pragma unroll
                for (int r = 0; r < 4; ++r)
                    sh.tv[tcol][trow + r] = f2bf(acc[m][n][r] + bv);
            }
        }
        __syncthreads();
        const int dlocal = tid >> 1;            // 0..127 (d column of tile)
        const int th     = (tid & 1) * 64;      // token half
        const int hd     = ((n0 - 2 * Cc) >> 6) + (dlocal >> 6);
        const int dl     = dlocal & 63;
        const int dt     = dl >> 4, lrv = dl & 15;
        const int token  = m0 + th;
        const int bq     = token >> 12;
        const int tile   = (token & (Tt - 1)) >> 6;
        unsigned short* tb = vpk + (size_t)((bq * Hh + hd) * 64 + tile) * 4096;
        #pragma unroll
        for (int cj = 0; cj < 8; ++cj) {
            int khv = cj >> 2, gv = cj & 3;
            unsigned short* dst = tb + (dt * 2 + khv) * 512 + (gv * 16 + lrv) * 8;
            *(short8*)dst = *(const short8*)&sh.tv[dlocal][th + cj * 8];
        }
        return;
    }

    if (BF16OUT && kpk != nullptr && n0 >= Cc) {
        // ---- K pack epilogue: acc -> LDS transposed [token][dcol] -> kpk ----
        #pragma unroll
        for (int n = 0; n < 4; ++n) {
            int tcol = wc * 64 + n * 16 + lr;
            float bv = bias[n0 + tcol];
            #pragma unroll
            for (int m = 0; m < 4; ++m) {
                int trow = wr * 64 + m * 16 + g * 4;
                #pragma unroll
                for (int r = 0; r < 4; ++r)
                    sh.tv[trow + r][tcol] = f2bf(acc[m][n][r] + bv);
            }
        }
        __syncthreads();
        #pragma unroll
        for (int c = 0; c < 8; ++c) {
            int s = tid + 256 * c;              // 0..2047
            int ln = s & 63;
            int f  = (s >> 6) & 7;
            int hh = (s >> 9) & 1;
            int sub = s >> 10;
            int khk = f >> 2, ktk = (f >> 1) & 1, ksk = f & 1;
            int gk = ln >> 4, lrk = ln & 15;
            int tokl = sub * 64 + khk * 32 + ktk * 16 + lrk;
            int dl   = hh * 64 + ksk * 32 + gk * 8;
            int token = m0 + sub * 64;
            int bq    = token >> 12;
            int tile  = (token & (Tt - 1)) >> 6;
            int hd    = ((n0 - Cc) >> 6) + hh;
            unsigned short* dst = kpk + (size_t)((bq * Hh + hd) * 64 + tile) * 4096
                                  + f * 512 + ln * 8;
            *(short8*)dst = *(const short8*)&sh.tv[tokl][dl];
        }
        return;
    }

    // ---- normal epilogue: Q columns (bf16, scaled) or fp32 out ----
    const float qscale = 0.125f * 1.44269504088896340736f;
    #pragma unroll
    for (int n = 0; n < 4; ++n) {
        int coln = n0 + wc * 64 + n * 16 + lr;
        float bv = bias[coln];
        #pragma unroll
        for (int m = 0; m < 4; ++m) {
            int rowb = m0 + wr * 64 + m * 16 + g * 4;
            #pragma unroll
            for (int r = 0; r < 4; ++r) {
                float v = acc[m][n][r] + bv;
                if (BF16OUT)
                    ((unsigned short*)Cout)[(size_t)(rowb + r) * Cc + coln] =
                        f2bf(v * qscale);
                else
                    ((float*)Cout)[(size_t)(rowb + r) * N + coln] = v;
            }
        }
    }
}

// ---------------------------------------------------------------------------
// Flash attention, 16x16x32 MFMA, swapped QK^T, fixed-shift softmax,
// zero-LDS K/V (L2-resident fragment-packed buffers), barrier-free K-loop,
// software pipeline depth 1 (K loads + QK one tile ahead).
// __launch_bounds__(512, 4): VGPR cap ~128 so the pipeline state fits with
// ZERO SPILLS (R17's (512,6) cap forced scratch spills -> 627 MB writes).
// 512 threads = 8 waves = 4 q-strips(16q) x 2 key-halves(32k); split-K
// partials combine by plain addition (fixed-shift) through LDS per pass.
// Causal PAIR scheduling (65-tile stream), XCD-colocated grid.
// ---------------------------------------------------------------------------
__global__ __launch_bounds__(512, 4)
void attn_mfma(const unsigned short* __restrict__ qb,
               const unsigned short* __restrict__ kpk,
               const unsigned short* __restrict__ vpk,
               unsigned short* __restrict__ outb) {
    // decode: id = xcd + 8*(P + 32*j), H2 = xcd + 8*j  (bijective, 768 blocks)
    const int nid  = blockIdx.x;
    const int xcd  = nid & 7;
    const int rest = nid >> 3;
    const int P    = rest & 31;                // pair: high 63-P, low P
    const int H2   = xcd + 8 * (rest >> 5);
    const int hd   = H2 % Hh;
    const int b    = H2 / Hh;
    const int tid = threadIdx.x;
    const int wid = tid >> 6, lane = tid & 63;
    const int strip = wid & 3, kh = wid >> 2;  // q-strip (16q), key-half (32k)
    const int lr = lane & 15, g = lane >> 4;

    __shared__ __align__(16) float combO[4][64][16];
    __shared__ float combL[4][64];

    const unsigned short* qbase = qb + (size_t)b * Tt * Cc;
    const unsigned short* kbase = kpk + (size_t)((b * Hh + hd) * 64) * 4096;
    const unsigned short* vbase = vpk + (size_t)((b * Hh + hd) * 64) * 4096;

    const int ntA = 64 - P;
    const int qA  = (63 - P) * 64 + strip * 16 + lr;
    const int qB  = P * 64 + strip * 16 + lr;

    // fragment offsets within a tile (ushorts)
    const int kfo = kh * 2048 + lane * 8;
    const int vfo = kh * 512 + lane * 8;

    short8 qf0, qf1;
    {
        const unsigned short* qp = qbase + (size_t)qA * Cc + hd * Dd;
        qf0 = *(const short8*)(qp + g * 8);
        qf1 = *(const short8*)(qp + 32 + g * 8);
    }

    const int laneA = lr + ((g & 1) << 5);     // src lane for P-relayout
    const int laneB = laneA + 16;
    const int asel  = g >> 1;

    f32x4 o[4];
    #pragma unroll
    for (int dt = 0; dt < 4; ++dt) o[dt] = (f32x4){0.f, 0.f, 0.f, 0.f};
    float lpart = 0.f;
    int myq = qA;

    auto combine_epilogue = [&]() {
        if (kh) {
            #pragma unroll
            for (int dt = 0; dt < 4; ++dt)
                *(f32x4*)&combO[strip][lane][dt * 4] = o[dt];
            combL[strip][lane] = lpart;
        }
        __syncthreads();
        if (!kh) {
            float l_r = lpart + combL[strip][lane];
            l_r += __shfl_xor(l_r, 16);
            l_r += __shfl_xor(l_r, 32);
            float inv = 1.f / fmaxf(l_r, 1e-37f);
            unsigned short* op = outb + ((size_t)b * Tt + myq) * Cc + hd * Dd + g * 4;
            #pragma unroll
            for (int dt = 0; dt < 4; ++dt) {
                f32x4 t2 = *(const f32x4*)&combO[strip][lane][dt * 4];
                u16x4 w;
                #pragma unroll
                for (int r = 0; r < 4; ++r) w[r] = f2bf((o[dt][r] + t2[r]) * inv);
                *(u16x4*)(op + dt * 16) = w;
            }
        }
        __syncthreads();
    };

    // ---- pipeline prologue: K frags + QK for tile stream index 0 ----
    f32x4 stn0, stn1;
    {
        short8 k0 = *(const short8*)(kbase + kfo);
        short8 k1 = *(const short8*)(kbase + kfo + 512);
        short8 k2 = *(const short8*)(kbase + kfo + 1024);
        short8 k3 = *(const short8*)(kbase + kfo + 1536);
        f32x4 a = (f32x4){0.f, 0.f, 0.f, 0.f};
        a = __builtin_amdgcn_mfma_f32_16x16x32_bf16(k0, qf0, a, 0, 0, 0);
        a = __builtin_amdgcn_mfma_f32_16x16x32_bf16(k1, qf1, a, 0, 0, 0);
        stn0 = a;
        a = (f32x4){0.f, 0.f, 0.f, 0.f};
        a = __builtin_amdgcn_mfma_f32_16x16x32_bf16(k2, qf0, a, 0, 0, 0);
        a = __builtin_amdgcn_mfma_f32_16x16x32_bf16(k3, qf1, a, 0, 0, 0);
        stn1 = a;
    }

    #pragma unroll 1
    for (int ts = 0; ts < 65; ++ts) {
        const int inA = (ts < ntA) ? 1 : 0;
        const int kbt = inA ? ts : ts - ntA;
        const int nt  = inA ? ntA : (65 - ntA);

        // current tile scores (pre-computed)
        f32x4 st[2];
        st[0] = stn0; st[1] = stn1;

        // ---- V frags for current tile (needed at PV; latency under softmax)
        const unsigned short* vt_ = vbase + (size_t)kbt * 4096;
        short8 vf0 = *(const short8*)(vt_ + vfo);
        short8 vf1 = *(const short8*)(vt_ + vfo + 1024);
        short8 vf2 = *(const short8*)(vt_ + vfo + 2048);
        short8 vf3 = *(const short8*)(vt_ + vfo + 3072);

        // ---- K frags for NEXT tile (consumed by QK below; L2 latency
        //      covered by softmax+relayout) ----
        short8 kn0, kn1, kn2, kn3;
        const int have_next = (ts + 1 < 65);
        if (have_next) {
            int tn = (ts + 1 < ntA) ? ts + 1 : ts + 1 - ntA;
            const unsigned short* kt_ = kbase + (size_t)tn * 4096;
            kn0 = *(const short8*)(kt_ + kfo);
            kn1 = *(const short8*)(kt_ + kfo + 512);
            kn2 = *(const short8*)(kt_ + kfo + 1024);
            kn3 = *(const short8*)(kt_ + kfo + 1536);
        }

        // ---- causal mask (diagonal tile of the current pass only) ----
        if (kbt == nt - 1) {
            #pragma unroll
            for (int kt = 0; kt < 2; ++kt)
                #pragma unroll
                for (int r = 0; r < 4; ++r)
                    if (kbt * 64 + kh * 32 + kt * 16 + g * 4 + r > myq)
                        st[kt][r] = -1e30f;
        }

        // ---- fixed-shift softmax ----
        float psum = 0.f;
        #pragma unroll
        for (int kt = 0; kt < 2; ++kt)
            #pragma unroll
            for (int r = 0; r < 4; ++r) {
                float p = ex2(st[kt][r]);
                st[kt][r] = p;
                psum += p;
            }
        lpart += psum;

        // ---- cvt + shfl issue (results needed after next-tile QK) ----
        unsigned up[2][2];
        #pragma unroll
        for (int kt = 0; kt < 2; ++kt) {
            asm("v_cvt_pk_bf16_f32 %0, %1, %2"
                : "=v"(up[kt][0]) : "v"(st[kt][0]), "v"(st[kt][1]));
            asm("v_cvt_pk_bf16_f32 %0, %1, %2"
                : "=v"(up[kt][1]) : "v"(st[kt][2]), "v"(st[kt][3]));
        }
        unsigned wa0 = __shfl(up[0][0], laneA);
        unsigned wb0 = __shfl(up[1][0], laneA);
        unsigned wa1 = __shfl(up[0][1], laneA);
        unsigned wb1 = __shfl(up[1][1], laneA);
        unsigned wa2 = __shfl(up[0][0], laneB);
        unsigned wb2 = __shfl(up[1][0], laneB);
        unsigned wa3 = __shfl(up[0][1], laneB);
        unsigned wb3 = __shfl(up[1][1], laneB);

        // ---- next-tile QK (independent MFMA work filling bpermute latency)
        if (have_next) {
            if (ts + 1 == ntA) {   // crossing into pass B: switch Q frags
                const unsigned short* qp = qbase + (size_t)qB * Cc + hd * Dd;
                qf0 = *(const short8*)(qp + g * 8);
                qf1 = *(const short8*)(qp + 32 + g * 8);
            }
            f32x4 a = (f32x4){0.f, 0.f, 0.f, 0.f};
            a = __builtin_amdgcn_mfma_f32_16x16x32_bf16(kn0, qf0, a, 0, 0, 0);
            a = __builtin_amdgcn_mfma_f32_16x16x32_bf16(kn1, qf1, a, 0, 0, 0);
            stn0 = a;
            a = (f32x4){0.f, 0.f, 0.f, 0.f};
            a = __builtin_amdgcn_mfma_f32_16x16x32_bf16(kn2, qf0, a, 0, 0, 0);
            a = __builtin_amdgcn_mfma_f32_16x16x32_bf16(kn3, qf1, a, 0, 0, 0);
            stn1 = a;
        }

        // ---- PV for current tile ----
        union { unsigned w[4]; short8 v; } pb;
        pb.w[0] = asel ? wb0 : wa0;
        pb.w[1] = asel ? wb1 : wa1;
        pb.w[2] = asel ? wb2 : wa2;
        pb.w[3] = asel ? wb3 : wa3;
        o[0] = __builtin_amdgcn_mfma_f32_16x16x32_bf16(vf0, pb.v, o[0], 0, 0, 0);
        o[1] = __builtin_amdgcn_mfma_f32_16x16x32_bf16(vf1, pb.v, o[1], 0, 0, 0);
        o[2] = __builtin_amdgcn_mfma_f32_16x16x32_bf16(vf2, pb.v, o[2], 0, 0, 0);
        o[3] = __builtin_amdgcn_mfma_f32_16x16x32_bf16(vf3, pb.v, o[3], 0, 0, 0);

        // ---- pass-A finish: combine key-halves, write out, reset for B ----
        if (ts == ntA - 1) {
            combine_epilogue();
            #pragma unroll
            for (int dt = 0; dt < 4; ++dt) o[dt] = (f32x4){0.f, 0.f, 0.f, 0.f};
            lpart = 0.f;
            myq = qB;
        }
    }

    combine_epilogue();
}

// ---------------------------------------------------------------------------
extern "C" void kernel_launch(void* const* d_in, const int* in_sizes, int n_in,
                              void* d_out, int out_size, void* d_ws, size_t ws_size,
                              hipStream_t stream) {
    const float* x    = (const float*)d_in[0];
    const float* Wqkv = (const float*)d_in[1];
    const float* bqkv = (const float*)d_in[2];
    const float* Wout = (const float*)d_in[3];
    const float* bout = (const float*)d_in[4];
    float* out = (float*)d_out;

    const int M = Bb * Tt;          // 8192
    const int N1 = 3 * Cc;          // 2304

    char* p = (char*)d_ws;
    unsigned short* qbuf  = (unsigned short*)p; p += (size_t)M * Cc * 2;        // Q rows
    unsigned short* xb    = (unsigned short*)p; p += (size_t)M * Cc * 2;
    unsigned short* wqkvt = (unsigned short*)p; p += (size_t)N1 * Cc * 2;
    unsigned short* woutt = (unsigned short*)p; p += (size_t)Cc * Cc * 2;
    unsigned short* kpk   = (unsigned short*)p; p += (size_t)Bb * Hh * 64 * 4096 * 2;
    unsigned short* vpk   = (unsigned short*)p; p += (size_t)Bb * Hh * 64 * 4096 * 2;
    unsigned short* attb  = (unsigned short*)p; p += (size_t)M * Cc * 2;

    cvt_bf16<<<dim3((M * Cc / 8 + 255) / 256), dim3(256), 0, stream>>>(x, xb, M * Cc / 8);
    transpose_w<<<dim3(N1 / 64, Cc / 64), dim3(256), 0, stream>>>(Wqkv, wqkvt, Cc, N1);
    transpose_w<<<dim3(Cc / 64, Cc / 64), dim3(256), 0, stream>>>(Wout, woutt, Cc, Cc);

    // qkv GEMM: Q -> qbuf rows (scaled), K -> kpk frags, V -> vpk frags
    gemm_mfma<true><<<dim3(N1 / 128, M / 128), dim3(256), 0, stream>>>(
        xb, wqkvt, bqkv, qbuf, M, N1, Cc, kpk, vpk);

    // 32 causal pairs of 64-q blocks per (b,h); XCD-colocated; zero-LDS KV;
    // software-pipelined tile stream.
    attn_mfma<<<dim3(32 * Hh * Bb), dim3(512), 0, stream>>>(qbuf, kpk, vpk, attb);

    gemm_mfma<false><<<dim3(Cc / 128, M / 128), dim3(256), 0, stream>>>(
        attb, woutt, bout, out, M, Cc, Cc, nullptr, nullptr);
}

// Round 20
// 191.258 us; speedup vs baseline: 2.6557x; 1.0365x over previous
//
#include <hip/hip_runtime.h>
#include <math.h>

#define Bb 2
#define Tt 4096
#define Cc 768
#define Hh 12
#define Dd 64

typedef __attribute__((ext_vector_type(8))) short short8;
typedef __attribute__((ext_vector_type(4))) float f32x4;
typedef __attribute__((ext_vector_type(4))) unsigned short u16x4;

static __device__ __forceinline__ unsigned short f2bf(float f) {
    unsigned u = __float_as_uint(f);
    u += 0x7FFF + ((u >> 16) & 1);          // round-to-nearest-even
    return (unsigned short)(u >> 16);
}

static __device__ __forceinline__ float ex2(float x) {
    return __builtin_amdgcn_exp2f(x);
}

static __device__ __forceinline__ void gload16(const void* g, void* l) {
    __builtin_amdgcn_global_load_lds(
        (const __attribute__((address_space(1))) unsigned*)g,
        (__attribute__((address_space(3))) unsigned*)l, 16, 0, 0);
}

// ---------------------------------------------------------------------------
// Fused prolog: x fp32->bf16 (blocks [0, 3072)), Wqkv transpose->bf16
// (blocks [3072, 3504)), Wout transpose->bf16 (blocks [3504, 3648)).
// One launch instead of three.
// ---------------------------------------------------------------------------
__global__ __launch_bounds__(256)
void prep(const float* __restrict__ x, unsigned short* __restrict__ xb,
          const float* __restrict__ Wqkv, unsigned short* __restrict__ wqkvt,
          const float* __restrict__ Wout, unsigned short* __restrict__ woutt) {
    __shared__ __align__(16) unsigned short Tl[64][72];
    const int CVT = (Bb * Tt * Cc / 8) / 256;       // 3072
    const int T1  = (3 * Cc / 64) * (Cc / 64);      // 432
    int bid = blockIdx.x;

    if (bid < CVT) {
        int i = bid * 256 + threadIdx.x;
        float4 a = *(const float4*)(x + (size_t)i * 8);
        float4 b = *(const float4*)(x + (size_t)i * 8 + 4);
        union { short8 v; unsigned short u[8]; } p;
        p.u[0] = f2bf(a.x); p.u[1] = f2bf(a.y); p.u[2] = f2bf(a.z); p.u[3] = f2bf(a.w);
        p.u[4] = f2bf(b.x); p.u[5] = f2bf(b.y); p.u[6] = f2bf(b.z); p.u[7] = f2bf(b.w);
        *(short8*)(xb + (size_t)i * 8) = p.v;
        return;
    }
    bid -= CVT;
    const float* W;
    unsigned short* Wt;
    int K, N, nb, kb;
    if (bid < T1) {
        W = Wqkv; Wt = wqkvt; K = Cc; N = 3 * Cc;
        nb = bid % (3 * Cc / 64); kb = bid / (3 * Cc / 64);
    } else {
        bid -= T1;
        W = Wout; Wt = woutt; K = Cc; N = Cc;
        nb = bid % (Cc / 64); kb = bid / (Cc / 64);
    }
    int n0 = nb * 64, k0 = kb * 64;
    int t = threadIdx.x;
    int r = t >> 2, c = (t & 3) * 16;
    const float* wp = W + (size_t)(k0 + r) * N + n0 + c;
    #pragma unroll
    for (int j = 0; j < 16; j += 4) {
        float4 v = *(const float4*)(wp + j);
        Tl[c + j + 0][r] = f2bf(v.x);
        Tl[c + j + 1][r] = f2bf(v.y);
        Tl[c + j + 2][r] = f2bf(v.z);
        Tl[c + j + 3][r] = f2bf(v.w);
    }
    __syncthreads();
    unsigned short* op = Wt + (size_t)(n0 + r) * K + k0 + c;
    *(short8*)op       = *(const short8*)&Tl[r][c];
    *(short8*)(op + 8) = *(const short8*)&Tl[r][c + 8];
}

// ---------------------------------------------------------------------------
// bf16 MFMA GEMM: C[M,N] = (A[M,K] @ Bt[N,K]^T + bias) * (col<qcols ? qscale : 1)
// 128x128 tile, BK=64, 256 threads (4 waves, 2x2), global_load_lds staging.
// For gemm1 V-columns (n0 >= voff): tile transposed through LDS into
// vtb[b][h][d][t] (fused repack).
// ---------------------------------------------------------------------------
template<bool BF16OUT>
__global__ __launch_bounds__(256)
void gemm_mfma(const unsigned short* __restrict__ A, const unsigned short* __restrict__ Bt,
               const float* __restrict__ bias, void* __restrict__ Cout,
               int M, int N, int K, int qcols,
               unsigned short* __restrict__ vtb, int voff) {
    union SmemU {
        unsigned short ab[2][128][64];   // staging: [0]=A tile, [1]=B tile
        unsigned short tv[128][136];     // transposed V epilogue (cols x rows, padded)
    };
    __shared__ __align__(16) SmemU sh;
    const int tid = threadIdx.x;
    const int wid = tid >> 6, lane = tid & 63;
    const int lr = lane & 15, g = lane >> 4;
    const int wr = wid >> 1, wc = wid & 1;
    const int m0 = blockIdx.y * 128, n0 = blockIdx.x * 128;
    const int srow = lane >> 3;
    const int scol = (lane & 7) * 8;

    f32x4 acc[4][4] = {};

    for (int k0 = 0; k0 < K; k0 += 64) {
        #pragma unroll
        for (int j = 0; j < 4; ++j) {
            int ci = wid * 4 + j;
            int row = ci * 8 + srow;
            gload16(A  + (size_t)(m0 + row) * K + k0 + scol, &sh.ab[0][ci * 8][0]);
            gload16(Bt + (size_t)(n0 + row) * K + k0 + scol, &sh.ab[1][ci * 8][0]);
        }
        __syncthreads();
        #pragma unroll
        for (int ks = 0; ks < 2; ++ks) {
            short8 af[4], bfr[4];
            #pragma unroll
            for (int m = 0; m < 4; ++m)
                af[m] = *(const short8*)&sh.ab[0][wr * 64 + m * 16 + lr][ks * 32 + g * 8];
            #pragma unroll
            for (int n = 0; n < 4; ++n)
                bfr[n] = *(const short8*)&sh.ab[1][wc * 64 + n * 16 + lr][ks * 32 + g * 8];
            #pragma unroll
            for (int m = 0; m < 4; ++m)
                #pragma unroll
                for (int n = 0; n < 4; ++n)
                    acc[m][n] = __builtin_amdgcn_mfma_f32_16x16x32_bf16(
                        af[m], bfr[n], acc[m][n], 0, 0, 0);
        }
        __syncthreads();
    }

    if (vtb != nullptr && n0 >= voff) {
        // ---- fused V-transpose epilogue: acc -> LDS (transposed) -> vtb ----
        #pragma unroll
        for (int n = 0; n < 4; ++n) {
            int tcol = wc * 64 + n * 16 + lr;
            float bv = bias[n0 + tcol];
            #pragma unroll
            for (int m = 0; m < 4; ++m) {
                int trow = wr * 64 + m * 16 + g * 4;
                #pragma unroll
                for (int r = 0; r < 4; ++r)
                    sh.tv[tcol][trow + r] = f2bf(acc[m][n][r] + bv);
            }
        }
        __syncthreads();
        const int dlocal = tid >> 1;            // 0..127 (column of tile)
        const int th     = (tid & 1) * 64;      // row half
        const int colg   = n0 + dlocal;
        const int hd     = (colg - voff) >> 6;
        const int d      = (colg - voff) & 63;
        const int token  = m0 + th;
        const int bq     = token >> 12;         // Tt = 4096
        const int t0     = token & (Tt - 1);
        unsigned short* dst = vtb + ((size_t)(bq * Hh + hd) * Dd + d) * Tt + t0;
        const unsigned short* src = &sh.tv[dlocal][th];
        #pragma unroll
        for (int j = 0; j < 8; ++j)
            *(short8*)(dst + j * 8) = *(const short8*)(src + j * 8);
        return;
    }

    // qscale = 0.125 * log2(e): QK^T scores land directly in log2 domain.
    const float qscale = 0.125f * 1.44269504088896340736f;
    #pragma unroll
    for (int n = 0; n < 4; ++n) {
        int coln = n0 + wc * 64 + n * 16 + lr;
        float bv = bias[coln];
        float sc = (coln < qcols) ? qscale : 1.0f;
        #pragma unroll
        for (int m = 0; m < 4; ++m) {
            int rowb = m0 + wr * 64 + m * 16 + g * 4;
            #pragma unroll
            for (int r = 0; r < 4; ++r) {
                float v = (acc[m][n][r] + bv) * sc;
                if (BF16OUT)
                    ((unsigned short*)Cout)[(size_t)(rowb + r) * N + coln] = f2bf(v);
                else
                    ((float*)Cout)[(size_t)(rowb + r) * N + coln] = v;
            }
        }
    }
}

// ---------------------------------------------------------------------------
// Flash attention, 16x16x32 MFMA, swapped QK^T, fixed-shift softmax
// (p = exp2(s) directly; scores bounded -> no max tracking; partials over
// ANY key partition combine by plain addition).
// SPLIT-K over keys: 512 threads = 8 waves = 4 q-strips x 2 key-halves.
// Causal PAIR scheduling (65-tile uniform stream), XCD-colocated grid,
// KV tile 64 keys, LDS double-buffered, XOR-swizzled, global_load_lds.
// ---------------------------------------------------------------------------
__global__ __launch_bounds__(512)
void attn_mfma(const unsigned short* __restrict__ qkvb,
               const unsigned short* __restrict__ vtb,
               unsigned short* __restrict__ outb) {
    // decode: id = xcd + 8*(P + 32*j), H2 = xcd + 8*j  (bijective, 768 blocks)
    const int nid  = blockIdx.x;
    const int xcd  = nid & 7;
    const int rest = nid >> 3;                 // 0..95
    const int P    = rest & 31;                // pair: high 63-P, low P
    const int H2   = xcd + 8 * (rest >> 5);    // 0..23
    const int hd   = H2 % Hh;
    const int b    = H2 / Hh;
    const int tid = threadIdx.x;
    const int wid = tid >> 6, lane = tid & 63;
    const int strip = wid & 3, kh = wid >> 2;  // q-strip, key-half
    const int lr = lane & 15, g = lane >> 4;
    const int rm7 = lr & 7;
    const size_t rs = 3 * Cc;

    __shared__ __align__(16) unsigned short Ks[2][64 * 64];   // K  [key][d], swizzled
    __shared__ __align__(16) unsigned short Vs[2][64 * 64];   // V^T [d][key], swizzled
    __shared__ __align__(16) float combO[4][64][16];          // key-half combine buf
    __shared__ float combL[4][64];

    const unsigned short* qkvbase = qkvb + (size_t)b * Tt * rs;
    const unsigned short* vbase   = vtb + (size_t)((b * Hh + hd) * Dd) * Tt;

    // staging: 512 threads cover 64 rows x 8 slots; phys slot tid&7 holds
    // logical slot (tid&7)^(row&7) (XOR involution)
    const int row0 = tid >> 3;                 // 0..63
    const int slog = (tid & 7) ^ (row0 & 7);
    const unsigned short* ksrc0 = qkvbase + (size_t)row0 * rs + Cc + hd * Dd + slog * 8;
    const unsigned short* vsrc0 = vbase + (size_t)row0 * Tt + slog * 8;

    const int ntA = 64 - P;                    // tiles for high q-block (63-P)
    const int qA  = (63 - P) * 64 + strip * 16 + lr;
    const int qB  = P * 64 + strip * 16 + lr;

    short8 qfA0, qfA1, qfB0, qfB1;
    {
        const unsigned short* qp = qkvbase + (size_t)qA * rs + hd * Dd;
        qfA0 = *(const short8*)(qp + g * 8);
        qfA1 = *(const short8*)(qp + 32 + g * 8);
        qp = qkvbase + (size_t)qB * rs + hd * Dd;
        qfB0 = *(const short8*)(qp + g * 8);
        qfB1 = *(const short8*)(qp + 32 + g * 8);
    }

    // stream tile ts -> kv tile (ts<ntA: pass A tile ts; else pass B tile ts-ntA)
    auto stage = [&](int buf, int ts) {
        int t = (ts < ntA) ? ts : ts - ntA;
        gload16(ksrc0 + (size_t)t * 64 * rs, &Ks[buf][wid * 512]);
        gload16(vsrc0 + t * 64,              &Vs[buf][wid * 512]);
    };

    stage(0, 0);
    __syncthreads();
    int cur = 0;

    const int laneA = lr + ((g & 1) << 5);     // src lane for P-relayout
    const int laneB = laneA + 16;
    const int asel  = g >> 1;

    f32x4 o[4];
    #pragma unroll
    for (int dt = 0; dt < 4; ++dt) o[dt] = (f32x4){0.f, 0.f, 0.f, 0.f};
    float lpart = 0.f;
    short8 qf0 = qfA0, qf1 = qfA1;
    int myq = qA;

    // combine the two key-halves' (O, l) partials; kh=0 wave writes out
    auto combine_epilogue = [&]() {
        if (kh) {
            #pragma unroll
            for (int dt = 0; dt < 4; ++dt)
                *(f32x4*)&combO[strip][lane][dt * 4] = o[dt];
            combL[strip][lane] = lpart;
        }
        __syncthreads();
        if (!kh) {
            float l_r = lpart + combL[strip][lane];
            l_r += __shfl_xor(l_r, 16);
            l_r += __shfl_xor(l_r, 32);
            float inv = 1.f / fmaxf(l_r, 1e-37f);
            unsigned short* op = outb + ((size_t)b * Tt + myq) * Cc + hd * Dd + g * 4;
            #pragma unroll
            for (int dt = 0; dt < 4; ++dt) {
                f32x4 t2 = *(const f32x4*)&combO[strip][lane][dt * 4];
                u16x4 w;
                #pragma unroll
                for (int r = 0; r < 4; ++r) w[r] = f2bf((o[dt][r] + t2[r]) * inv);
                *(u16x4*)(op + dt * 16) = w;
            }
        }
        __syncthreads();
    };

    #pragma unroll 1
    for (int ts = 0; ts < 65; ++ts) {
        if (ts + 1 < 65) stage(cur ^ 1, ts + 1);

        const int inA = (ts < ntA) ? 1 : 0;
        const int kbt = inA ? ts : ts - ntA;
        const int nt  = inA ? ntA : (65 - ntA);
        const unsigned short* Kc = &Ks[cur][0];
        const unsigned short* Vc = &Vs[cur][0];

        // ---- S^T = K Q^T for this wave's 32-key half (2 x 16-key blocks) ----
        f32x4 st[2];
        __builtin_amdgcn_s_setprio(1);
        #pragma unroll
        for (int kt = 0; kt < 2; ++kt) {
            int row = kh * 32 + kt * 16 + lr;
            int off0 = row * 64 + (g ^ rm7) * 8;
            short8 kf0 = *(const short8*)&Kc[off0];
            short8 kf1 = *(const short8*)&Kc[off0 ^ 32];
            f32x4 a = (f32x4){0.f, 0.f, 0.f, 0.f};
            a = __builtin_amdgcn_mfma_f32_16x16x32_bf16(kf0, qf0, a, 0, 0, 0);
            a = __builtin_amdgcn_mfma_f32_16x16x32_bf16(kf1, qf1, a, 0, 0, 0);
            st[kt] = a;
        }
        __builtin_amdgcn_s_setprio(0);

        // ---- causal mask (diagonal tile of the current pass only) ----
        if (kbt == nt - 1) {
            #pragma unroll
            for (int kt = 0; kt < 2; ++kt)
                #pragma unroll
                for (int r = 0; r < 4; ++r)
                    if (kbt * 64 + kh * 32 + kt * 16 + g * 4 + r > myq)
                        st[kt][r] = -1e30f;
        }

        // ---- fixed-shift softmax: p = exp2(s); accumulate l partial ----
        float psum = 0.f;
        #pragma unroll
        for (int kt = 0; kt < 2; ++kt)
            #pragma unroll
            for (int r = 0; r < 4; ++r) {
                float p = ex2(st[kt][r]);
                st[kt][r] = p;
                psum += p;
            }
        lpart += psum;

        // ---- P^T -> PV B-frag (32 local keys), cvt_pk + shfl ----
        unsigned up[2][2];
        #pragma unroll
        for (int kt = 0; kt < 2; ++kt) {
            asm("v_cvt_pk_bf16_f32 %0, %1, %2"
                : "=v"(up[kt][0]) : "v"(st[kt][0]), "v"(st[kt][1]));
            asm("v_cvt_pk_bf16_f32 %0, %1, %2"
                : "=v"(up[kt][1]) : "v"(st[kt][2]), "v"(st[kt][3]));
        }
        {
            unsigned wa0 = __shfl(up[0][0], laneA);
            unsigned wb0 = __shfl(up[1][0], laneA);
            unsigned wa1 = __shfl(up[0][1], laneA);
            unsigned wb1 = __shfl(up[1][1], laneA);
            unsigned wa2 = __shfl(up[0][0], laneB);
            unsigned wb2 = __shfl(up[1][0], laneB);
            unsigned wa3 = __shfl(up[0][1], laneB);
            unsigned wb3 = __shfl(up[1][1], laneB);
            union { unsigned w[4]; short8 v; } pb;
            pb.w[0] = asel ? wb0 : wa0;
            pb.w[1] = asel ? wb1 : wa1;
            pb.w[2] = asel ? wb2 : wa2;
            pb.w[3] = asel ? wb3 : wa3;
            __builtin_amdgcn_s_setprio(1);
            #pragma unroll
            for (int dt = 0; dt < 4; ++dt) {
                int row = dt * 16 + lr;
                int off = row * 64 + (((kh << 2) | g) ^ rm7) * 8;
                short8 vf = *(const short8*)&Vc[off];
                o[dt] = __builtin_amdgcn_mfma_f32_16x16x32_bf16(vf, pb.v, o[dt], 0, 0, 0);
            }
            __builtin_amdgcn_s_setprio(0);
        }

        __syncthreads();
        cur ^= 1;

        // ---- pass-A finish: combine key-halves, write out, reset for B ----
        if (ts == ntA - 1) {
            combine_epilogue();
            #pragma unroll
            for (int dt = 0; dt < 4; ++dt) o[dt] = (f32x4){0.f, 0.f, 0.f, 0.f};
            lpart = 0.f;
            qf0 = qfB0; qf1 = qfB1;
            myq = qB;
        }
    }

    combine_epilogue();
}

// ---------------------------------------------------------------------------
extern "C" void kernel_launch(void* const* d_in, const int* in_sizes, int n_in,
                              void* d_out, int out_size, void* d_ws, size_t ws_size,
                              hipStream_t stream) {
    const float* x    = (const float*)d_in[0];
    const float* Wqkv = (const float*)d_in[1];
    const float* bqkv = (const float*)d_in[2];
    const float* Wout = (const float*)d_in[3];
    const float* bout = (const float*)d_in[4];
    float* out = (float*)d_out;

    const int M = Bb * Tt;          // 8192
    const int N1 = 3 * Cc;          // 2304

    char* p = (char*)d_ws;
    unsigned short* qkvb  = (unsigned short*)p; p += (size_t)M * N1 * 2;
    unsigned short* xb    = (unsigned short*)p; p += (size_t)M * Cc * 2;
    unsigned short* wqkvt = (unsigned short*)p; p += (size_t)N1 * Cc * 2;
    unsigned short* woutt = (unsigned short*)p; p += (size_t)Cc * Cc * 2;
    unsigned short* vtb   = (unsigned short*)p; p += (size_t)Bb * Hh * Dd * Tt * 2;
    unsigned short* attb  = (unsigned short*)p; p += (size_t)M * Cc * 2;

    // fused prolog: x->bf16 + both weight transposes in one launch
    const int prepBlocks = (M * Cc / 8) / 256 + (N1 / 64) * (Cc / 64)
                           + (Cc / 64) * (Cc / 64);
    prep<<<dim3(prepBlocks), dim3(256), 0, stream>>>(x, xb, Wqkv, wqkvt, Wout, woutt);

    // qkv = x @ Wqkv + bqkv; Q cols pre-scaled by 0.125*log2(e) (bf16 out);
    // V cols (>=1536) transposed in-epilogue straight into vtb.
    gemm_mfma<true><<<dim3(N1 / 128, M / 128), dim3(256), 0, stream>>>(
        xb, wqkvt, bqkv, qkvb, M, N1, Cc, Cc, vtb, 2 * Cc);

    // 32 causal pairs of 64-q blocks per (b,h); XCD-colocated 1-D grid;
    // 8 waves/block = 4 q-strips x 2 key-halves (split-K over keys).
    attn_mfma<<<dim3(32 * Hh * Bb), dim3(512), 0, stream>>>(qkvb, vtb, attb);

    gemm_mfma<false><<<dim3(Cc / 128, M / 128), dim3(256), 0, stream>>>(
        attb, woutt, bout, out, M, Cc, Cc, 0, nullptr, 1 << 30);
}